// Round 8
// baseline (136.013 us; speedup 1.0000x reference)
//
#include <hip/hip_runtime.h>

#define B_ 16
#define T_ 2048
#define NP 10000
#define NH 128

/* ws float offsets. XF: frag-ready fp16 plane of X[b,t]=A[pseq[b,t]] (4MB) */
#define XF_F   0
#define NLAM_F 1048576
#define GG_F   1081344
#define SS_F   1114112

typedef __attribute__((ext_vector_type(8))) _Float16 f16x8;
typedef __attribute__((ext_vector_type(4))) float f32x4;

// shorts offset of frag slot: (b, 16-row group R, K-half ks); 512 shorts/frag
__device__ __forceinline__ size_t xfbase(int b, int R, int ks) {
  return (((size_t)b * 128 + R) * 2 + ks) * 512;
}

// ---- prep: X -> frag-ready fp16 plane; per-(b,t) -lam / guess / slip (fp32 exact)
__global__ __launch_bounds__(256) void prep(
    const int* __restrict__ pseq, const float* __restrict__ A,
    const float* __restrict__ kcw,
    const float* __restrict__ lam_w, const float* __restrict__ lam_b,
    const float* __restrict__ guess_w, const float* __restrict__ guess_b,
    const float* __restrict__ slip_w, const float* __restrict__ slip_b,
    float* __restrict__ ws) {
  const int tid = threadIdx.x, bid = blockIdx.x;
  const int lane = tid & 63, wv = tid >> 6;
  __shared__ float wvec[3][64];
  if (tid < 192) {          // every block: fold kc (kcw reads hit L2)
    int vec = tid >> 6, k = tid & 63;
    const float* wvp = (vec == 0) ? lam_w : (vec == 1 ? guess_w : slip_w);
    float acc = 0.f;
    #pragma unroll 8
    for (int h = 0; h < NH; ++h) acc = fmaf(kcw[k * NH + h], wvp[h], acc);
    wvec[vec][k] = acc;
  }
  {  // wave W -> (b, R, ks). Lane l: row R*16+(l&15), elems ks*32+(l>>4)*8 .. +8
    const int W = bid * 4 + wv;            // [0, 4096)
    const int b = W >> 8, rem = W & 255, R = rem >> 1, ks = rem & 1;
    const int row = (R << 4) + (lane & 15), gp = lane >> 4;
    const float* src = A + (size_t)pseq[b * T_ + row] * 64 + ks * 32 + gp * 8;
    float4 v0 = *(const float4*)src;
    float4 v1 = *(const float4*)(src + 4);
    float vv[8] = {v0.x, v0.y, v0.z, v0.w, v1.x, v1.y, v1.z, v1.w};
    union { _Float16 h[8]; f16x8 v; } H;
    #pragma unroll
    for (int i = 0; i < 8; ++i) H.h[i] = (_Float16)vv[i];   // RNE
    *(f16x8*)((unsigned short*)ws + xfbase(b, R, ks) + lane * 8) = H.v;
  }
  __syncthreads();
  if (tid < 32) {           // heads: 32 per block x 1024 blocks = 32768 (b,t)
    const int tg = bid * 32 + tid;
    const float* xr = A + ((size_t)pseq[tg] << 6);
    float aL = 0.f, aG = 0.f, aS = 0.f;
    #pragma unroll
    for (int k = 0; k < 64; ++k) {
      float xv = xr[k];
      aL = fmaf(xv, wvec[0][k], aL);
      aG = fmaf(xv, wvec[1][k], aG);
      aS = fmaf(xv, wvec[2][k], aS);
    }
    ws[NLAM_F + tg] = -__expf(aL + lam_b[0]);
    ws[GG_F + tg]   = 1.f / (1.f + __expf(-(aG + guess_b[0])));
    ws[SS_F + tg]   = 1.f / (1.f + __expf(-(aS + slip_b[0])));
  }
}

// ---- main: block = (b,tile), 256 thr / 4 waves; 4-way descending chunk split;
// fp16 MFMA; two-pass epilogue (recompute from acc -> low VGPR, no spill);
// in-register cross-chunk fold; LDS combine. 3 blocks/CU resident.
__global__ __launch_bounds__(256, 3) void mainK(
    const float* __restrict__ y, float* __restrict__ ws,
    float* __restrict__ out) {
  __shared__ float part[4][3][64];
  const int tid = threadIdx.x, bid = blockIdx.x;
  const int lane = tid & 63;
  const int wv = __builtin_amdgcn_readfirstlane(tid >> 6);   // 0..3
  const int u = bid & 255, half = bid >> 8;
  const int b = u >> 4, kk = u & 15;
  const int tile = half ? kk : 31 - kk;     // heavy+light pairing across rounds
  const int t0 = tile << 6, base = b * T_;
  const int c = lane & 15, g = lane >> 4;
  const unsigned short* X = (const unsigned short*)ws;

  float nl[4];
  #pragma unroll
  for (int fj = 0; fj < 4; ++fj) nl[fj] = ws[NLAM_F + base + t0 + 16 * fj + c];

  // B-frags depend only on tile: load once (8 frags, 32 VGPRs)
  f16x8 bfr[2][2][2];  // [fjh][j2][ks]
  #pragma unroll
  for (int fjh = 0; fjh < 2; ++fjh)
    #pragma unroll
    for (int j2 = 0; j2 < 2; ++j2)
      #pragma unroll
      for (int ks = 0; ks < 2; ++ks)
        bfr[fjh][j2][ks] = *(const f16x8*)(X + xfbase(b, tile * 4 + 2 * fjh + j2, ks) + lane * 8);

  const int nchunks = tile + 1;
  const int nc = (nchunks + 3) >> 2;
  const int cLo = wv * nc;
  const int cHi = min(cLo + nc, nchunks);

  float NA[4] = {0,0,0,0}, DA[4] = {0,0,0,0}, RA[4] = {0,0,0,0};

  for (int cc = cHi - 1; cc >= cLo; --cc) {   // descending s
    const bool diag = (cc == tile);
    float yy[4][4];
    #pragma unroll
    for (int fi = 0; fi < 4; ++fi) {
      float4 t4 = *(const float4*)(y + base + (cc << 6) + 16 * fi + 4 * g);
      yy[fi][0] = t4.x; yy[fi][1] = t4.y; yy[fi][2] = t4.z; yy[fi][3] = t4.w;
    }
    #pragma unroll
    for (int fjh = 0; fjh < 2; ++fjh) {
      f32x4 acc[4][2] = {};
      #pragma unroll
      for (int ks = 0; ks < 2; ++ks) {
        f16x8 afr[4];
        #pragma unroll
        for (int fi = 0; fi < 4; ++fi)
          afr[fi] = *(const f16x8*)(X + xfbase(b, cc * 4 + fi, ks) + lane * 8);
        #pragma unroll
        for (int fi = 0; fi < 4; ++fi)
          #pragma unroll
          for (int j2 = 0; j2 < 2; ++j2)
            acc[fi][j2] = __builtin_amdgcn_mfma_f32_16x16x32_f16(afr[fi], bfr[fjh][j2][ks], acc[fi][j2], 0, 0, 0);
      }
      #pragma unroll
      for (int j2 = 0; j2 < 2; ++j2) {
        const int fj = 2 * fjh + j2;
        // pass 1: fragment totals + cross-lane suffixes (C: col=c (t), row=4g+rr (s))
        float S[4], ft[4];
        #pragma unroll
        for (int fi = 0; fi < 4; ++fi) {
          f32x4 v = acc[fi][j2];
          if (diag) {
            #pragma unroll
            for (int rr = 0; rr < 4; ++rr)
              if (16 * fi + 4 * g + rr >= 16 * fj + c) v[rr] = 0.f;
          }
          const float p0 = ((v.x + v.y) + (v.z + v.w));
          const float u16 = __shfl_xor(p0, 16);
          const float pr = p0 + u16;
          const float u32 = __shfl_xor(pr, 32);
          ft[fi] = pr + u32;
          S[fi] = ((g & 1) ? 0.f : u16) + ((g < 2) ? u32 : 0.f);
        }
        const float F2 = ft[3], F1 = F2 + ft[2], F0 = F1 + ft[1];
        const float Fv[4] = {F0, F1, F2, 0.f};
        // pass 2: per-element exp + num/den (recompute mask+suffix from live acc)
        float num = 0.f, den = 0.f;
        #pragma unroll
        for (int fi = 0; fi < 4; ++fi) {
          f32x4 v = acc[fi][j2];
          if (diag) {
            #pragma unroll
            for (int rr = 0; rr < 4; ++rr)
              if (16 * fi + 4 * g + rr >= 16 * fj + c) v[rr] = 0.f;
          }
          const float SF = S[fi] + Fv[fi];
          float p3 = v.w, p2 = p3 + v.z, p1 = p2 + v.y, p0 = p1 + v.x;
          const float pp[4] = {p0, p1, p2, p3};
          const float sm[4] = {v.x, v.y, v.z, v.w};
          #pragma unroll
          for (int rr = 0; rr < 4; ++rr) {
            const float e = __expf(nl[fj] * (pp[rr] + SF));
            const float w = sm[rr] * e;
            den += w;
            num = fmaf(yy[fi][rr], w, num);
          }
        }
        num += __shfl_xor(num, 16); num += __shfl_xor(num, 32);
        den += __shfl_xor(den, 16); den += __shfl_xor(den, 32);
        const float tot = Fv[0] + ft[0];
        const float e = __expf(nl[fj] * RA[fj]);    // fold chunk (higher-s first)
        NA[fj] = fmaf(num, e, NA[fj]);
        DA[fj] = fmaf(den, e, DA[fj]);
        RA[fj] += tot;
      }
    }
  }

  if (g == 0) {
    #pragma unroll
    for (int fj = 0; fj < 4; ++fj) {
      part[wv][0][16 * fj + c] = NA[fj];
      part[wv][1][16 * fj + c] = DA[fj];
      part[wv][2][16 * fj + c] = RA[fj];
    }
  }
  __syncthreads();

  if (wv == 0) {   // fold 4 wave ranges (wave 3 = highest s), epilogue, store
    const int t = t0 + lane;
    const float nlt = ws[NLAM_F + base + t];
    float N = 0.f, D = 0.f, Roff = 0.f;
    #pragma unroll
    for (int w = 3; w >= 0; --w) {
      const float e = __expf(nlt * Roff);
      N = fmaf(part[w][0][lane], e, N);
      D = fmaf(part[w][1][lane], e, D);
      Roff += part[w][2][lane];
    }
    const float gv = ws[GG_F + base + t];
    const float sv = ws[SS_F + base + t];
    const float h = N / (D + 1e-6f);
    float yh = h * (1.f - sv) + (1.f - h) * gv;
    out[base + t] = fminf(fmaxf(yh, 0.01f), 0.99f);
  }
}

extern "C" void kernel_launch(void* const* d_in, const int* in_sizes, int n_in,
                              void* d_out, int out_size, void* d_ws, size_t ws_size,
                              hipStream_t stream) {
  const float* y    = (const float*)d_in[0];
  const int*   pseq = (const int*)  d_in[1];
  const float* A    = (const float*)d_in[2];
  const float* kcw  = (const float*)d_in[3];
  const float* lw   = (const float*)d_in[4];
  const float* lb   = (const float*)d_in[5];
  const float* gw   = (const float*)d_in[6];
  const float* gb   = (const float*)d_in[7];
  const float* sw   = (const float*)d_in[8];
  const float* sb   = (const float*)d_in[9];
  float* out = (float*)d_out;
  float* ws  = (float*)d_ws;   // ~4.6 MB used

  prep<<<1024, 256, 0, stream>>>(pseq, A, kcw, lw, lb, gw, gb, sw, sb, ws);
  mainK<<<512, 256, 0, stream>>>(y, ws, out);
}

// Round 9
// 121.015 us; speedup vs baseline: 1.1239x; 1.1239x over previous
//
#include <hip/hip_runtime.h>

#define B_ 16
#define T_ 2048
#define NP 10000
#define NH 128
#define ITEMS_PER_B 528            /* sum_{tile=0}^{31}(tile+1) */
#define N_ITEMS (B_ * ITEMS_PER_B) /* 8448 equal wave items */

/* ws float offsets. XF: frag-ready fp16 plane of X[b,t]=A[pseq[b,t]] (4MB) */
#define XF_F   0
#define NLAM_F 1048576
#define GG_F   1081344
#define SS_F   1114112
#define PART_F 1146880   /* 8448*192 floats of (num,den,tot) partials */

typedef __attribute__((ext_vector_type(8))) _Float16 f16x8;
typedef __attribute__((ext_vector_type(4))) float f32x4;

// shorts offset of frag slot: (b, 16-row group R, K-half ks); 512 shorts/frag
__device__ __forceinline__ size_t xfbase(int b, int R, int ks) {
  return (((size_t)b * 128 + R) * 2 + ks) * 512;
}

// ---- prep: X -> frag-ready fp16 plane; per-(b,t) -lam / guess / slip (fp32 exact)
__global__ __launch_bounds__(256) void prep(
    const int* __restrict__ pseq, const float* __restrict__ A,
    const float* __restrict__ kcw,
    const float* __restrict__ lam_w, const float* __restrict__ lam_b,
    const float* __restrict__ guess_w, const float* __restrict__ guess_b,
    const float* __restrict__ slip_w, const float* __restrict__ slip_b,
    float* __restrict__ ws) {
  const int tid = threadIdx.x, bid = blockIdx.x;
  const int lane = tid & 63, wv = tid >> 6;
  __shared__ float wvec[3][64];
  if (tid < 192) {          // fold kc (kcw reads hit L2)
    int vec = tid >> 6, k = tid & 63;
    const float* wvp = (vec == 0) ? lam_w : (vec == 1 ? guess_w : slip_w);
    float acc = 0.f;
    #pragma unroll 8
    for (int h = 0; h < NH; ++h) acc = fmaf(kcw[k * NH + h], wvp[h], acc);
    wvec[vec][k] = acc;
  }
  {  // wave W -> (b, R, ks). Lane l: row R*16+(l&15), elems ks*32+(l>>4)*8 .. +8
    const int W = bid * 4 + wv;            // [0, 4096)
    const int b = W >> 8, rem = W & 255, R = rem >> 1, ks = rem & 1;
    const int row = (R << 4) + (lane & 15), gp = lane >> 4;
    const float* src = A + (size_t)pseq[b * T_ + row] * 64 + ks * 32 + gp * 8;
    float4 v0 = *(const float4*)src;
    float4 v1 = *(const float4*)(src + 4);
    float vv[8] = {v0.x, v0.y, v0.z, v0.w, v1.x, v1.y, v1.z, v1.w};
    union { _Float16 h[8]; f16x8 v; } H;
    #pragma unroll
    for (int i = 0; i < 8; ++i) H.h[i] = (_Float16)vv[i];   // RNE
    *(f16x8*)((unsigned short*)ws + xfbase(b, R, ks) + lane * 8) = H.v;
  }
  __syncthreads();
  if (tid < 32) {           // heads: 32 per block x 1024 blocks = 32768 (b,t)
    const int tg = bid * 32 + tid;
    const float* xr = A + ((size_t)pseq[tg] << 6);
    float aL = 0.f, aG = 0.f, aS = 0.f;
    #pragma unroll
    for (int k = 0; k < 64; ++k) {
      float xv = xr[k];
      aL = fmaf(xv, wvec[0][k], aL);
      aG = fmaf(xv, wvec[1][k], aG);
      aS = fmaf(xv, wvec[2][k], aS);
    }
    ws[NLAM_F + tg] = -__expf(aL + lam_b[0]);
    ws[GG_F + tg]   = 1.f / (1.f + __expf(-(aG + guess_b[0])));
    ws[SS_F + tg]   = 1.f / (1.f + __expf(-(aS + slip_b[0])));
  }
}

// ---- main: one wave = one (b,tile,chunk) item. Straight-line, no LDS, no
// loop-carried deps -> all 16 frag loads hoisted by compiler; latency hidden
// by 33 waves/CU demand + ILP. Writes (num,den,tot) partials to ws.
__global__ __launch_bounds__(256, 3) void mainF(
    const float* __restrict__ y, float* __restrict__ ws) {
  const int tid = threadIdx.x;
  const int lane = tid & 63;
  const int wv = __builtin_amdgcn_readfirstlane(tid >> 6);
  const int item = blockIdx.x * 4 + wv;           // [0, 8448)
  const int b = item / ITEMS_PER_B;
  const int r0 = item - b * ITEMS_PER_B;
  int tile = (int)((sqrtf(8.f * (float)r0 + 1.f) - 1.f) * 0.5f);
  while ((tile + 1) * (tile + 2) / 2 <= r0) ++tile;
  while (tile * (tile + 1) / 2 > r0) --tile;
  const int chunk = r0 - tile * (tile + 1) / 2;
  const int t0 = tile << 6, base = b * T_;
  const int c = lane & 15, g = lane >> 4;
  const bool diag = (chunk == tile);
  const unsigned short* X = (const unsigned short*)ws;

  float nl[4];
  #pragma unroll
  for (int fj = 0; fj < 4; ++fj) nl[fj] = ws[NLAM_F + base + t0 + 16 * fj + c];

  f16x8 bfr[4][2];   // [j][ks] B-frags for the 4 t-column fragments
  #pragma unroll
  for (int j = 0; j < 4; ++j)
    #pragma unroll
    for (int ks = 0; ks < 2; ++ks)
      bfr[j][ks] = *(const f16x8*)(X + xfbase(b, tile * 4 + j, ks) + lane * 8);

  float yy[4][4];
  #pragma unroll
  for (int fi = 0; fi < 4; ++fi) {
    float4 t4 = *(const float4*)(y + base + (chunk << 6) + 16 * fi + 4 * g);
    yy[fi][0] = t4.x; yy[fi][1] = t4.y; yy[fi][2] = t4.z; yy[fi][3] = t4.w;
  }

  float NUM[4], DEN[4], TOT[4];
  #pragma unroll
  for (int fjh = 0; fjh < 2; ++fjh) {
    f32x4 acc[4][2] = {};
    #pragma unroll
    for (int ks = 0; ks < 2; ++ks) {
      f16x8 afr[4];
      #pragma unroll
      for (int fi = 0; fi < 4; ++fi)
        afr[fi] = *(const f16x8*)(X + xfbase(b, chunk * 4 + fi, ks) + lane * 8);
      #pragma unroll
      for (int fi = 0; fi < 4; ++fi)
        #pragma unroll
        for (int j2 = 0; j2 < 2; ++j2)
          acc[fi][j2] = __builtin_amdgcn_mfma_f32_16x16x32_f16(afr[fi], bfr[2 * fjh + j2][ks], acc[fi][j2], 0, 0, 0);
    }
    #pragma unroll
    for (int j2 = 0; j2 < 2; ++j2) {
      const int fj = 2 * fjh + j2;
      // pass 1: fragment totals + cross-lane suffixes (C: col=c (t), row=4g+rr (s))
      float S[4], ft[4];
      #pragma unroll
      for (int fi = 0; fi < 4; ++fi) {
        f32x4 v = acc[fi][j2];
        if (diag) {
          #pragma unroll
          for (int rr = 0; rr < 4; ++rr)
            if (16 * fi + 4 * g + rr >= 16 * fj + c) v[rr] = 0.f;
        }
        const float p0 = ((v.x + v.y) + (v.z + v.w));
        const float u16 = __shfl_xor(p0, 16);
        const float pr = p0 + u16;
        const float u32 = __shfl_xor(pr, 32);
        ft[fi] = pr + u32;
        S[fi] = ((g & 1) ? 0.f : u16) + ((g < 2) ? u32 : 0.f);
      }
      const float F2 = ft[3], F1 = F2 + ft[2], F0 = F1 + ft[1];
      const float Fv[4] = {F0, F1, F2, 0.f};
      // pass 2: per-element exp + num/den (recompute mask+suffix from live acc)
      float num = 0.f, den = 0.f;
      #pragma unroll
      for (int fi = 0; fi < 4; ++fi) {
        f32x4 v = acc[fi][j2];
        if (diag) {
          #pragma unroll
          for (int rr = 0; rr < 4; ++rr)
            if (16 * fi + 4 * g + rr >= 16 * fj + c) v[rr] = 0.f;
        }
        const float SF = S[fi] + Fv[fi];
        float p3 = v.w, p2 = p3 + v.z, p1 = p2 + v.y, p0 = p1 + v.x;
        const float pp[4] = {p0, p1, p2, p3};
        const float sm[4] = {v.x, v.y, v.z, v.w};
        #pragma unroll
        for (int rr = 0; rr < 4; ++rr) {
          const float e = __expf(nl[fj] * (pp[rr] + SF));
          const float w = sm[rr] * e;
          den += w;
          num = fmaf(yy[fi][rr], w, num);
        }
      }
      num += __shfl_xor(num, 16); num += __shfl_xor(num, 32);
      den += __shfl_xor(den, 16); den += __shfl_xor(den, 32);
      NUM[fj] = num; DEN[fj] = den; TOT[fj] = Fv[0] + ft[0];
    }
  }
  float* po = ws + PART_F + (size_t)item * 192;
  if (g == 0) {
    #pragma unroll
    for (int fj = 0; fj < 4; ++fj) {
      po[16 * fj + c] = NUM[fj];
      po[64 + 16 * fj + c] = DEN[fj];
      po[128 + 16 * fj + c] = TOT[fj];
    }
  }
}

// ---- phase2: one wave per (b,tile): fold chunks descending, epilogue, store.
__global__ __launch_bounds__(256) void phase2(
    const float* __restrict__ ws, float* __restrict__ out) {
  const int tid = threadIdx.x;
  const int lane = tid & 63;
  const int widx = blockIdx.x * 4 + (tid >> 6);   // [0, 512)
  const int b = widx >> 5, tile = widx & 31;
  const int t = (tile << 6) + lane, base = b * T_;
  const float nlt = ws[NLAM_F + base + t];
  const int ibase = b * ITEMS_PER_B + tile * (tile + 1) / 2;
  float N = 0.f, D = 0.f, Roff = 0.f;
  for (int cc = tile; cc >= 0; --cc) {            // descending s
    const float* p = ws + PART_F + (size_t)(ibase + cc) * 192;
    const float e = __expf(nlt * Roff);
    N = fmaf(p[lane], e, N);
    D = fmaf(p[64 + lane], e, D);
    Roff += p[128 + lane];
  }
  const float gv = ws[GG_F + base + t];
  const float sv = ws[SS_F + base + t];
  const float h = N / (D + 1e-6f);
  float yh = h * (1.f - sv) + (1.f - h) * gv;
  out[base + t] = fminf(fmaxf(yh, 0.01f), 0.99f);
}

extern "C" void kernel_launch(void* const* d_in, const int* in_sizes, int n_in,
                              void* d_out, int out_size, void* d_ws, size_t ws_size,
                              hipStream_t stream) {
  const float* y    = (const float*)d_in[0];
  const int*   pseq = (const int*)  d_in[1];
  const float* A    = (const float*)d_in[2];
  const float* kcw  = (const float*)d_in[3];
  const float* lw   = (const float*)d_in[4];
  const float* lb   = (const float*)d_in[5];
  const float* gw   = (const float*)d_in[6];
  const float* gb   = (const float*)d_in[7];
  const float* sw   = (const float*)d_in[8];
  const float* sb   = (const float*)d_in[9];
  float* out = (float*)d_out;
  float* ws  = (float*)d_ws;   // ~11.1 MB used

  prep<<<1024, 256, 0, stream>>>(pseq, A, kcw, lw, lb, gw, gb, sw, sb, ws);
  mainF<<<N_ITEMS / 4, 256, 0, stream>>>(y, ws);
  phase2<<<128, 256, 0, stream>>>(ws, out);
}

// Round 13
// 116.514 us; speedup vs baseline: 1.1674x; 1.0386x over previous
//
#include <hip/hip_runtime.h>

#define B_ 16
#define T_ 2048
#define NP 10000
#define NH 128

/* ws float offsets. XF: frag-ready fp16 plane of X[b,t]=A[pseq[b,t]] (4MB) */
#define XF_F   0
#define NLAM_F 1048576
#define GG_F   1081344
#define SS_F   1114112

typedef __attribute__((ext_vector_type(8))) _Float16 f16x8;
typedef __attribute__((ext_vector_type(4))) float f32x4;

// shorts offset of frag slot: (b, 16-row group R, K-half ks); 512 shorts/frag
__device__ __forceinline__ size_t xfbase(int b, int R, int ks) {
  return (((size_t)b * 128 + R) * 2 + ks) * 512;
}

// ---- prep (single-sweep): X -> frag-ready fp16 AND per-(b,t) heads from the
// same registers. Wave (b,R,ks) lane (c,g) holds A[row=R*16+c][ks*32+g*8..+8];
// head dot = butterfly over g (4 lanes) + LDS combine of the two ks-halves.
__global__ __launch_bounds__(256) void prep(
    const int* __restrict__ pseq, const float* __restrict__ A,
    const float* __restrict__ kcw,
    const float* __restrict__ lam_w, const float* __restrict__ lam_b,
    const float* __restrict__ guess_w, const float* __restrict__ guess_b,
    const float* __restrict__ slip_w, const float* __restrict__ slip_b,
    float* __restrict__ ws) {
  const int tid = threadIdx.x, bid = blockIdx.x;
  const int lane = tid & 63, wv = tid >> 6;
  __shared__ float wvec[3][64];
  __shared__ float half_[4][3][16];
  if (tid < 192) {          // fold kc @ {lam,guess,slip} (small, L2-hit)
    int vec = tid >> 6, k = tid & 63;
    const float* wvp = (vec == 0) ? lam_w : (vec == 1 ? guess_w : slip_w);
    float acc = 0.f;
    #pragma unroll 8
    for (int h = 0; h < NH; ++h) acc = fmaf(kcw[k * NH + h], wvp[h], acc);
    wvec[vec][k] = acc;
  }
  __syncthreads();

  const int W = bid * 4 + wv;            // [0, 4096) = 16 b x 128 R x 2 ks
  const int b = W >> 8, rem = W & 255, R = rem >> 1, ks = rem & 1;
  const int c = lane & 15, g = lane >> 4;
  const int row = (R << 4) + c;
  const float* src = A + (size_t)pseq[b * T_ + row] * 64 + ks * 32 + g * 8;
  float4 v0 = *(const float4*)src;
  float4 v1 = *(const float4*)(src + 4);
  float vv[8] = {v0.x, v0.y, v0.z, v0.w, v1.x, v1.y, v1.z, v1.w};
  union { _Float16 h[8]; f16x8 v; } H;
  #pragma unroll
  for (int i = 0; i < 8; ++i) H.h[i] = (_Float16)vv[i];   // RNE
  *(f16x8*)((unsigned short*)ws + xfbase(b, R, ks) + lane * 8) = H.v;

  // head partial dots from the same vv registers
  const int k0 = ks * 32 + g * 8;
  float pL = 0.f, pG = 0.f, pS = 0.f;
  #pragma unroll
  for (int i = 0; i < 8; ++i) {
    pL = fmaf(vv[i], wvec[0][k0 + i], pL);
    pG = fmaf(vv[i], wvec[1][k0 + i], pG);
    pS = fmaf(vv[i], wvec[2][k0 + i], pS);
  }
  pL += __shfl_xor(pL, 16); pL += __shfl_xor(pL, 32);   // reduce over g
  pG += __shfl_xor(pG, 16); pG += __shfl_xor(pG, 32);
  pS += __shfl_xor(pS, 16); pS += __shfl_xor(pS, 32);
  if (g == 0) {
    half_[wv][0][c] = pL; half_[wv][1][c] = pG; half_[wv][2][c] = pS;
  }
  __syncthreads();
  if ((wv & 1) == 0 && g == 0) {   // even wave pairs with wv+1 (same R, other ks)
    const int tg = b * T_ + (R << 4) + c;
    const float aL = half_[wv][0][c] + half_[wv + 1][0][c];
    const float aG = half_[wv][1][c] + half_[wv + 1][1][c];
    const float aS = half_[wv][2][c] + half_[wv + 1][2][c];
    ws[NLAM_F + tg] = -__expf(aL + lam_b[0]);
    ws[GG_F + tg]   = 1.f / (1.f + __expf(-(aG + guess_b[0])));
    ws[SS_F + tg]   = 1.f / (1.f + __expf(-(aS + slip_b[0])));
  }
}

// ---- main: block = (b,tile); 8 waves own descending chunk ranges; fp16 MFMA;
// B-frags hoisted out of chunk loop; in-register cross-chunk fold; LDS combine.
// (Byte-identical structure to the verified R7 kernel.)
__global__ __launch_bounds__(512, 2) void mainK(
    const float* __restrict__ y, float* __restrict__ ws,
    float* __restrict__ out) {
  __shared__ float part[8][3][64];
  const int tid = threadIdx.x, bid = blockIdx.x;
  const int lane = tid & 63;
  const int wv = __builtin_amdgcn_readfirstlane(tid >> 6);
  const int u = bid & 255, half = bid >> 8;
  const int b = u >> 4, kk = u & 15;
  const int tile = half ? kk : 31 - kk;     // heavy+light pairing per CU
  const int t0 = tile << 6, base = b * T_;
  const int c = lane & 15, g = lane >> 4;
  const unsigned short* X = (const unsigned short*)ws;

  float nl[4];
  #pragma unroll
  for (int fj = 0; fj < 4; ++fj) nl[fj] = ws[NLAM_F + base + t0 + 16 * fj + c];

  // B-frags depend only on tile: load once (8 frags, 32 VGPRs)
  f16x8 bfr[2][2][2];  // [fjh][j2][ks]
  #pragma unroll
  for (int fjh = 0; fjh < 2; ++fjh)
    #pragma unroll
    for (int j2 = 0; j2 < 2; ++j2)
      #pragma unroll
      for (int ks = 0; ks < 2; ++ks)
        bfr[fjh][j2][ks] = *(const f16x8*)(X + xfbase(b, tile * 4 + 2 * fjh + j2, ks) + lane * 8);

  const int nchunks = tile + 1;
  const int nc = (nchunks + 7) >> 3;
  const int cLo = wv * nc;
  const int cHi = min(cLo + nc, nchunks);

  float NA[4] = {0,0,0,0}, DA[4] = {0,0,0,0}, RA[4] = {0,0,0,0};

  for (int cc = cHi - 1; cc >= cLo; --cc) {   // descending s
    const bool diag = (cc == tile);
    float yy[4][4];
    #pragma unroll
    for (int fi = 0; fi < 4; ++fi) {
      float4 t4 = *(const float4*)(y + base + (cc << 6) + 16 * fi + 4 * g);
      yy[fi][0] = t4.x; yy[fi][1] = t4.y; yy[fi][2] = t4.z; yy[fi][3] = t4.w;
    }
    #pragma unroll
    for (int fjh = 0; fjh < 2; ++fjh) {
      f32x4 acc[4][2] = {};
      #pragma unroll
      for (int ks = 0; ks < 2; ++ks) {
        f16x8 afr[4];
        #pragma unroll
        for (int fi = 0; fi < 4; ++fi)
          afr[fi] = *(const f16x8*)(X + xfbase(b, cc * 4 + fi, ks) + lane * 8);
        #pragma unroll
        for (int fi = 0; fi < 4; ++fi)
          #pragma unroll
          for (int j2 = 0; j2 < 2; ++j2)
            acc[fi][j2] = __builtin_amdgcn_mfma_f32_16x16x32_f16(afr[fi], bfr[fjh][j2][ks], acc[fi][j2], 0, 0, 0);
      }
      #pragma unroll
      for (int j2 = 0; j2 < 2; ++j2) {
        const int fj = 2 * fjh + j2;
        float sm[4][4], pp[4][4], S[4], ft[4];
        #pragma unroll
        for (int fi = 0; fi < 4; ++fi) {      // C layout: col=c (t), row=4g+rr (s)
          f32x4 v = acc[fi][j2];
          if (diag) {                         // strictly-past mask
            #pragma unroll
            for (int rr = 0; rr < 4; ++rr)
              if (16 * fi + 4 * g + rr >= 16 * fj + c) v[rr] = 0.f;
          }
          sm[fi][0]=v.x; sm[fi][1]=v.y; sm[fi][2]=v.z; sm[fi][3]=v.w;
          float p3 = v.w, p2 = p3 + v.z, p1 = p2 + v.y, p0 = p1 + v.x;
          pp[fi][0]=p0; pp[fi][1]=p1; pp[fi][2]=p2; pp[fi][3]=p3;
          float u16 = __shfl_xor(p0, 16);     // butterfly over row-groups
          float pr = p0 + u16;
          float u32 = __shfl_xor(pr, 32);
          ft[fi] = pr + u32;                  // fragment total
          S[fi] = ((g & 1) ? 0.f : u16) + ((g < 2) ? u32 : 0.f);
        }
        const float F2 = ft[3], F1 = F2 + ft[2], F0 = F1 + ft[1];
        const float Fv[4] = {F0, F1, F2, 0.f};
        float num = 0.f, den = 0.f;
        #pragma unroll
        for (int fi = 0; fi < 4; ++fi) {
          const float SF = S[fi] + Fv[fi];
          #pragma unroll
          for (int rr = 0; rr < 4; ++rr) {
            const float e = __expf(nl[fj] * (pp[fi][rr] + SF));
            const float w = sm[fi][rr] * e;
            den += w;
            num = fmaf(yy[fi][rr], w, num);
          }
        }
        num += __shfl_xor(num, 16); num += __shfl_xor(num, 32);
        den += __shfl_xor(den, 16); den += __shfl_xor(den, 32);
        const float tot = Fv[0] + ft[0];
        const float e = __expf(nl[fj] * RA[fj]);    // fold chunk (higher-s first)
        NA[fj] = fmaf(num, e, NA[fj]);
        DA[fj] = fmaf(den, e, DA[fj]);
        RA[fj] += tot;
      }
    }
  }

  if (g == 0) {
    #pragma unroll
    for (int fj = 0; fj < 4; ++fj) {
      part[wv][0][16 * fj + c] = NA[fj];
      part[wv][1][16 * fj + c] = DA[fj];
      part[wv][2][16 * fj + c] = RA[fj];
    }
  }
  __syncthreads();

  if (wv == 0) {   // fold 8 wave ranges (wave 7 = highest s), epilogue, store
    const int t = t0 + lane;
    const float nlt = ws[NLAM_F + base + t];
    float N = 0.f, D = 0.f, Roff = 0.f;
    #pragma unroll
    for (int w = 7; w >= 0; --w) {
      const float e = __expf(nlt * Roff);
      N = fmaf(part[w][0][lane], e, N);
      D = fmaf(part[w][1][lane], e, D);
      Roff += part[w][2][lane];
    }
    const float gv = ws[GG_F + base + t];
    const float sv = ws[SS_F + base + t];
    const float h = N / (D + 1e-6f);
    float yh = h * (1.f - sv) + (1.f - h) * gv;
    out[base + t] = fminf(fmaxf(yh, 0.01f), 0.99f);
  }
}

extern "C" void kernel_launch(void* const* d_in, const int* in_sizes, int n_in,
                              void* d_out, int out_size, void* d_ws, size_t ws_size,
                              hipStream_t stream) {
  const float* y    = (const float*)d_in[0];
  const int*   pseq = (const int*)  d_in[1];
  const float* A    = (const float*)d_in[2];
  const float* kcw  = (const float*)d_in[3];
  const float* lw   = (const float*)d_in[4];
  const float* lb   = (const float*)d_in[5];
  const float* gw   = (const float*)d_in[6];
  const float* gb   = (const float*)d_in[7];
  const float* sw   = (const float*)d_in[8];
  const float* sb   = (const float*)d_in[9];
  float* out = (float*)d_out;
  float* ws  = (float*)d_ws;   // ~4.6 MB used

  prep<<<1024, 256, 0, stream>>>(pseq, A, kcw, lw, lb, gw, gb, sw, sb, ws);
  mainK<<<512, 512, 0, stream>>>(y, ws, out);
}